// Round 15
// baseline (290.245 us; speedup 1.0000x reference)
//
#include <hip/hip_runtime.h>

typedef unsigned short u16;
typedef __bf16 bf16x8 __attribute__((ext_vector_type(8)));
typedef float f32x4 __attribute__((ext_vector_type(4)));

#define SEQ   2048
#define DDIM  1024
#define EDIM  2048
#define FDIM  4224   /* 2E + S_ATT */
#define SATT  128
#define NBATCH 4

__device__ __forceinline__ u16 f2bf(float f) {
  unsigned u = __float_as_uint(f);
  unsigned r = (u + 0x7fffu + ((u >> 16) & 1u)) >> 16;
  return (u16)r;
}
__device__ __forceinline__ float bf2f(u16 v) {
  return __uint_as_float(((unsigned)v) << 16);
}

__device__ __forceinline__ void gload16(const u16* g, u16* l) {
  auto gp = (const __attribute__((address_space(1))) u16*)(unsigned long long)g;
  auto lp = (__attribute__((address_space(3))) u16*)(unsigned)(unsigned long long)l;
  __builtin_amdgcn_global_load_lds(gp, lp, 16, 0, 0);
}

// ---------------- elementwise / small kernels ----------------

__global__ void cvt_bf16_kernel(const float* __restrict__ in, u16* __restrict__ out, int n4) {
  int i = blockIdx.x * blockDim.x + threadIdx.x;
  if (i >= n4) return;
  float4 v = reinterpret_cast<const float4*>(in)[i];
  unsigned p0 = (unsigned)f2bf(v.x) | ((unsigned)f2bf(v.y) << 16);
  unsigned p1 = (unsigned)f2bf(v.z) | ((unsigned)f2bf(v.w) << 16);
  uint2 pk; pk.x = p0; pk.y = p1;
  reinterpret_cast<uint2*>(out)[i] = pk;
}

__global__ void rms_kernel(const float* __restrict__ x, const float* __restrict__ ln_g,
                           u16* __restrict__ xn) {
  int row = blockIdx.x;
  int t = threadIdx.x;
  const float4* xr = reinterpret_cast<const float4*>(x + (size_t)row * DDIM);
  float4 v = xr[t];
  float s = v.x * v.x + v.y * v.y + v.z * v.z + v.w * v.w;
#pragma unroll
  for (int off = 32; off > 0; off >>= 1) s += __shfl_down(s, off);
  __shared__ float wsum[4];
  int lane = t & 63, wv = t >> 6;
  if (lane == 0) wsum[wv] = s;
  __syncthreads();
  float tot = wsum[0] + wsum[1] + wsum[2] + wsum[3];
  float rms = sqrtf(tot * (1.0f / (float)DDIM));
  float scale = ln_g[0] / fmaxf(rms, 1e-5f);
  unsigned p0 = (unsigned)f2bf(v.x * scale) | ((unsigned)f2bf(v.y * scale) << 16);
  unsigned p1 = (unsigned)f2bf(v.z * scale) | ((unsigned)f2bf(v.w * scale) << 16);
  uint2 pk; pk.x = p0; pk.y = p1;
  reinterpret_cast<uint2*>(xn + (size_t)row * DDIM)[t] = pk;
}

// fallback-path q/k kernel (FULL path fuses this into gemm0's epilogue)
__global__ void qk_kernel(const u16* __restrict__ uv, const float* __restrict__ pos_enc,
                          const float* __restrict__ gamma, const float* __restrict__ beta,
                          u16* __restrict__ q, u16* __restrict__ k, int ldF) {
  int r = blockIdx.x;
  int t = threadIdx.x;
  int s = r & (SEQ - 1);
  float bval = bf2f(uv[(size_t)r * ldF + 2 * EDIM + t]);
  float pe = pos_enc[(size_t)s * SATT + t];
  float qv = bval * gamma[t] + beta[t] + pe;
  float kv = bval * gamma[SATT + t] + beta[SATT + t] + pe;
  q[(size_t)r * SATT + t] = f2bf(qv);
  k[(size_t)r * SATT + t] = f2bf(kv);
}

// vt[b][e][s] = uv[b][s][E + e] -- 64x64 tiles, 256 thr, 16 u16/thread.
// LDS pad 68: row stride 136 B (8B-aligned for uint2; 2-way bank alias on
// column reads = free per m136).
__global__ void transpose_v(const u16* __restrict__ uv, u16* __restrict__ vt, int ldF) {
  __shared__ u16 tile[64][68];
  int b = blockIdx.z;
  uv += (size_t)b * SEQ * ldF;
  vt += (size_t)b * EDIM * SEQ;
  int e0 = blockIdx.x * 64, s0 = blockIdx.y * 64;
  int t = threadIdx.x;
  int r = t >> 2;            // 0..63
  int c = (t & 3) << 4;      // 0,16,32,48
  const u16* src = uv + (size_t)(s0 + r) * ldF + EDIM + e0 + c;
#pragma unroll
  for (int p = 0; p < 4; p++)
    *reinterpret_cast<uint2*>(&tile[r][c + p * 4]) =
        *reinterpret_cast<const uint2*>(src + p * 4);
  __syncthreads();
  u16 buf[16];
#pragma unroll
  for (int j = 0; j < 16; j++) buf[j] = tile[c + j][r];
  u16* dst = vt + (size_t)(e0 + r) * SEQ + s0 + c;
#pragma unroll
  for (int p = 0; p < 4; p++)
    *reinterpret_cast<uint2*>(dst + p * 4) = *reinterpret_cast<uint2*>(&buf[p * 4]);
}

// ======== GEMM v4 (R8-proven: single-barrier tile, compiler-scheduled) =====
// C = A(M,K)*B(N,K)^T. BM=BN=256 (last col-tile may be ragged 128), BK=64,
// 512 thr = 8 waves (2 wm x 4 wn), per-wave 128x64.
// LDS 128 KiB = 2 dbuf x 4 panels of 16 KiB. Classic double buffer; at tile
// t top stage t+1 -> buf^1, then all ds_reads + MFMAs compiler-scheduled;
// boundary = vmcnt(0) + s_barrier + sched_barrier(0). XOR swizzle
// byte^=(row&7)<<4 on ds_read; inverse pre-applied to global staging source.
// Block mapping: R8's bn = li % nbx (bm-grouped variant of R14 regressed).
// EPI==0 extra: the ragged block (bn==16, cols N-128..N-1 = base) fuses q/k
// generation (q=base*g0+b0+pe, k=base*g1+b1+pe) into the epilogue.
template <int EPI>
__global__ __launch_bounds__(512, 2) void gemm_bt3(
    const u16* __restrict__ A, const u16* __restrict__ B,
    int N, int K,
    u16* __restrict__ Cbf,
    const u16* __restrict__ U, int ldu,
    const float* __restrict__ pos_enc, const float* __restrict__ gamma,
    const float* __restrict__ beta, u16* __restrict__ qout, u16* __restrict__ kout,
    size_t sA, size_t sB, size_t sC, size_t sU) {
  __shared__ u16 lds[65536];  // 128 KiB
  const int tid = threadIdx.x;
  const int w = tid >> 6, l = tid & 63;
  const int wm2 = w >> 2, wn2 = w & 3;
  const int fr = l & 15, kg = l >> 4;

  const int bz = blockIdx.z;
  A += (size_t)bz * sA; B += (size_t)bz * sB; U += (size_t)bz * sU;

  // XCD-aware bijective swizzle (nwg % 8 == 0 for all launched shapes)
  const int nbx = gridDim.x;
  int li = blockIdx.y * nbx + blockIdx.x;
  const int cpx = (nbx * gridDim.y) >> 3;
  li = (li & 7) * cpx + (li >> 3);
  const int bn = li % nbx;
  const int bm = li / nbx;

  const int NT = K >> 6;                     // even for all callers
  const bool full = (bn * 256 + 256 <= N);   // block-uniform ragged flag

  const int r0 = (w << 3) + (l >> 3);                  // staging row 0..63
  const int cswz = (((l & 7) ^ (l >> 3)) & 7) << 3;    // inv-swizzled col

  // staging pointers: 4 panels x 2 row-groups; advance 128 elems / 2 tiles
  const u16* pA00 = A + (size_t)bm * 256 * K + (size_t)r0 * K + cswz;
  const u16* pA01 = pA00 + (size_t)64 * K;
  const u16* pA10 = pA00 + (size_t)128 * K;
  const u16* pA11 = pA00 + (size_t)192 * K;
  const u16* pB00 = B + (size_t)bn * 256 * K + (size_t)r0 * K + cswz;
  const u16* pB01 = pB00 + (size_t)64 * K;
  const u16* pB10 = pB00 + (size_t)128 * K;
  const u16* pB11 = pB00 + (size_t)192 * K;

  // precomputed swizzled LDS read bases
  const int X  = (l & 7) << 4;
  const int Y0 = (kg << 4) ^ X;
  const int Y1 = ((kg << 4) | 64) ^ X;
  const char* ldsC = (const char*)lds;
  const char* aR0 = ldsC + wm2 * 8192 + fr * 128 + Y0;
  const char* aR1 = ldsC + wm2 * 8192 + fr * 128 + Y1;
  const char* bR0 = ldsC + 32768 + wn2 * 4096 + fr * 128 + Y0;
  const char* bR1 = ldsC + 32768 + wn2 * 4096 + fr * 128 + Y1;

  // LDS stage destination: word off = buf*32768 + p*8192 + w*512 (+4096 L1)
  auto stg = [&](int bufw, int p, const u16* g0, const u16* g1, int ofs) {
    u16* d = lds + bufw * 32768 + p * 8192 + w * 512;
    gload16(g0 + ofs, d);
    gload16(g1 + ofs, d + 4096);
  };

  f32x4 acc[8][4];
#pragma unroll
  for (int i = 0; i < 8; i++)
#pragma unroll
    for (int j = 0; j < 4; j++) acc[i][j] = f32x4{0.f, 0.f, 0.f, 0.f};

  // prologue: stage tile 0 -> buf0; drain; barrier
  stg(0, 0, pA00, pA01, 0); stg(0, 2, pB00, pB01, 0);
  if (full) stg(0, 3, pB10, pB11, 0);
  stg(0, 1, pA10, pA11, 0);
  asm volatile("s_waitcnt vmcnt(0)" ::: "memory");
  __builtin_amdgcn_s_barrier();
  __builtin_amdgcn_sched_barrier(0);

  bf16x8 aH[4][2], bF[2][2][2];  // bF[qb][j][s]

#define MFMA_Q(QA, QB)                                                        \
  _Pragma("unroll") for (int s = 0; s < 2; s++)                               \
  _Pragma("unroll") for (int i = 0; i < 4; i++)                               \
  _Pragma("unroll") for (int j = 0; j < 2; j++)                               \
    acc[(QA)*4 + i][(QB)*2 + j] = __builtin_amdgcn_mfma_f32_16x16x32_bf16(    \
        aH[i][s], bF[QB][j][s], acc[(QA)*4 + i][(QB)*2 + j], 0, 0, 0);

#define TILE_STEP(BUF, ST, OFS)                                               \
  {                                                                           \
    if (ST) {                                                                 \
      stg((BUF) ^ 1, 0, pA00, pA01, OFS);                                     \
      stg((BUF) ^ 1, 2, pB00, pB01, OFS);                                     \
      if (full) stg((BUF) ^ 1, 3, pB10, pB11, OFS);                           \
      stg((BUF) ^ 1, 1, pA10, pA11, OFS);                                     \
    }                                                                         \
    _Pragma("unroll") for (int i = 0; i < 4; i++) {                           \
      aH[i][0] = *(const bf16x8*)(aR0 + (BUF) * 65536 + i * 2048);            \
      aH[i][1] = *(const bf16x8*)(aR1 + (BUF) * 65536 + i * 2048);            \
    }                                                                         \
    _Pragma("unroll") for (int j = 0; j < 2; j++) {                           \
      bF[0][j][0] = *(const bf16x8*)(bR0 + (BUF) * 65536 + j * 2048);         \
      bF[0][j][1] = *(const bf16x8*)(bR1 + (BUF) * 65536 + j * 2048);         \
    }                                                                         \
    MFMA_Q(0, 0)                                                              \
    if (full) {                                                               \
      _Pragma("unroll") for (int j = 0; j < 2; j++) {                         \
        bF[1][j][0] = *(const bf16x8*)(bR0 + (BUF) * 65536 + 16384 + j * 2048);\
        bF[1][j][1] = *(const bf16x8*)(bR1 + (BUF) * 65536 + 16384 + j * 2048);\
      }                                                                       \
      MFMA_Q(0, 1)                                                            \
    }                                                                         \
    _Pragma("unroll") for (int i = 0; i < 4; i++) {                           \
      aH[i][0] = *(const bf16x8*)(aR0 + (BUF) * 65536 + 16384 + i * 2048);    \
      aH[i][1] = *(const bf16x8*)(aR1 + (BUF) * 65536 + 16384 + i * 2048);    \
    }                                                                         \
    MFMA_Q(1, 0)                                                              \
    if (full) { MFMA_Q(1, 1) }                                                \
    asm volatile("s_waitcnt vmcnt(0)" ::: "memory");                          \
    __builtin_amdgcn_s_barrier();                                             \
    __builtin_amdgcn_sched_barrier(0);                                        \
  }

  for (int t2 = 0; t2 < NT; t2 += 2) {
    const bool st0 = (t2 + 1 < NT);
    const bool st1 = (t2 + 2 < NT);
    TILE_STEP(0, st0, 64)
    TILE_STEP(1, st1, 128)
    pA00 += 128; pA01 += 128; pA10 += 128; pA11 += 128;
    pB00 += 128; pB01 += 128; pB10 += 128; pB11 += 128;
  }
#undef TILE_STEP
#undef MFMA_Q

  // epilogue
  const int rsub = (l >> 4) * 4;
  const int ccol = l & 15;
#pragma unroll
  for (int ai = 0; ai < 8; ai++) {
#pragma unroll
    for (int bj = 0; bj < 4; bj++) {
      if (!full && bj >= 2) continue;
      int n = bn * 256 + (bj >> 1) * 128 + wn2 * 32 + (bj & 1) * 16 + ccol;
#pragma unroll
      for (int tt = 0; tt < 4; tt++) {
        int m = bm * 256 + (ai >> 2) * 128 + wm2 * 64 + (ai & 3) * 16 + rsub + tt;
        float v = acc[ai][bj][tt];
        size_t idx = (size_t)m * N + n;
        if constexpr (EPI == 0) {
          float sv = v / (1.f + __expf(-v));
          Cbf[(size_t)bz * sC + idx] = f2bf(sv);
          if (!full) {  // base cols: fused q/k generation
            int nn = n - (N - SATT);
            int s = m & (SEQ - 1);
            float pe = pos_enc[(size_t)s * SATT + nn];
            qout[(size_t)m * SATT + nn] = f2bf(sv * gamma[nn] + beta[nn] + pe);
            kout[(size_t)m * SATT + nn] = f2bf(sv * gamma[SATT + nn] + beta[SATT + nn] + pe);
          }
        } else if constexpr (EPI == 1) {
          float sc = v * 0.08838834764831845f;  // 1/sqrt(128)
          sc = sc > 0.f ? sc * sc : 0.f;
          Cbf[(size_t)bz * sC + idx] = f2bf(sc);
        } else {
          float uvl = bf2f(U[(size_t)m * ldu + n]);
          Cbf[(size_t)bz * sC + idx] = f2bf(v * uvl);
        }
      }
    }
  }
}

// ======== 256x128 deep-pipeline GEMM (gemm3; round-3 proven) ====
template <int EPI>
__global__ __launch_bounds__(512, 2) void gemm_bt2(
    const u16* __restrict__ A, const u16* __restrict__ B,
    int M, int N, int K,
    u16* __restrict__ Cbf, float* __restrict__ Cf,
    const u16* __restrict__ U, int ldu,
    const float* __restrict__ Xres, const float* __restrict__ rscale,
    size_t sA, size_t sB, size_t sC, size_t sU) {
  __shared__ u16 lds[3 * 24576];  // 144 KiB
  const int tid = threadIdx.x;
  const int w = tid >> 6, l = tid & 63;
  const int wr = w >> 1, wc = w & 1;
  const int fr = l & 15, kg = l >> 4;

  const int bz = blockIdx.z;
  A += (size_t)bz * sA; B += (size_t)bz * sB; U += (size_t)bz * sU;

  const int nbx = gridDim.x;
  int li = blockIdx.y * nbx + blockIdx.x;
  const int cpx = (nbx * gridDim.y) >> 3;
  li = (li & 7) * cpx + (li >> 3);
  const int bn = li % nbx;
  const int bm = li / nbx;

  const int NT = K >> 6;
  const int srow = (w << 3) + (l >> 3);
  const int scol = (((l & 7) ^ (l >> 3)) & 7) << 3;
  const size_t aoff = (size_t)bm * 256 * K;
  const size_t boff = (size_t)bn * 128 * K;
  const char* ldsC = (const char*)lds;

  auto stageAu = [&](int t, int h) {
    int sb = (t % 3) * 24576 + h * 8192;
    const u16* g = A + aoff + (size_t)(h * 128 + srow) * K + t * 64 + scol;
#pragma unroll
    for (int L = 0; L < 2; L++)
      gload16(g + (size_t)(L * 64) * K, &lds[sb + (L * 8 + w) * 512]);
  };
  auto stageBu = [&](int t) {
    int sb = (t % 3) * 24576 + 16384;
    const u16* g = B + boff + (size_t)srow * K + t * 64 + scol;
#pragma unroll
    for (int L = 0; L < 2; L++)
      gload16(g + (size_t)(L * 64) * K, &lds[sb + (L * 8 + w) * 512]);
  };
  auto ldA = [&](int cur, int i, int s) -> bf16x8 {
    int r = ((wr & 1) << 6) + (i << 4) + fr;
    int off = cur * 49152 + ((wr >> 1) << 14) + (r << 7) + (s << 6) + (kg << 4);
    off ^= (r & 7) << 4;
    return *(const bf16x8*)(ldsC + off);
  };
  auto ldB = [&](int cur, int j, int s) -> bf16x8 {
    int r = (wc << 6) + (j << 4) + fr;
    int off = cur * 49152 + 32768 + (r << 7) + (s << 6) + (kg << 4);
    off ^= (r & 7) << 4;
    return *(const bf16x8*)(ldsC + off);
  };

  f32x4 acc[4][4];
#pragma unroll
  for (int i = 0; i < 4; i++)
#pragma unroll
    for (int j = 0; j < 4; j++) acc[i][j] = f32x4{0.f, 0.f, 0.f, 0.f};

  stageAu(0, 0); stageAu(0, 1); stageBu(0);
  if (NT > 1) { stageAu(1, 0); stageAu(1, 1); stageBu(1); }
  asm volatile("s_waitcnt vmcnt(6)" ::: "memory");
  __builtin_amdgcn_s_barrier();

  bf16x8 aF[2][2], bF[2][2][2];
  for (int t = 0; t < NT; ++t) {
    const int cur = t % 3;
    const bool st = (t + 2 < NT);
#pragma unroll
    for (int i = 0; i < 2; i++)
#pragma unroll
      for (int s = 0; s < 2; s++) aF[i][s] = ldA(cur, i, s);
#pragma unroll
    for (int j = 0; j < 2; j++)
#pragma unroll
      for (int s = 0; s < 2; s++) bF[0][j][s] = ldB(cur, j, s);
    if (st) stageAu(t + 2, 0);
    __builtin_amdgcn_s_barrier();
    __builtin_amdgcn_s_setprio(1);
#pragma unroll
    for (int s = 0; s < 2; s++)
#pragma unroll
      for (int i = 0; i < 2; i++)
#pragma unroll
        for (int j = 0; j < 2; j++)
          acc[i][j] = __builtin_amdgcn_mfma_f32_16x16x32_bf16(aF[i][s], bF[0][j][s], acc[i][j], 0, 0, 0);
    __builtin_amdgcn_s_setprio(0);
    __builtin_amdgcn_s_barrier();
#pragma unroll
    for (int j = 0; j < 2; j++)
#pragma unroll
      for (int s = 0; s < 2; s++) bF[1][j][s] = ldB(cur, 2 + j, s);
    if (st) stageAu(t + 2, 1);
    __builtin_amdgcn_s_barrier();
    __builtin_amdgcn_s_setprio(1);
#pragma unroll
    for (int s = 0; s < 2; s++)
#pragma unroll
      for (int i = 0; i < 2; i++)
#pragma unroll
        for (int j = 0; j < 2; j++)
          acc[i][2 + j] = __builtin_amdgcn_mfma_f32_16x16x32_bf16(aF[i][s], bF[1][j][s], acc[i][2 + j], 0, 0, 0);
    __builtin_amdgcn_s_setprio(0);
    __builtin_amdgcn_s_barrier();
#pragma unroll
    for (int i = 0; i < 2; i++)
#pragma unroll
      for (int s = 0; s < 2; s++) aF[i][s] = ldA(cur, 2 + i, s);
    if (st) stageBu(t + 2);
    __builtin_amdgcn_s_barrier();
    __builtin_amdgcn_s_setprio(1);
#pragma unroll
    for (int s = 0; s < 2; s++)
#pragma unroll
      for (int i = 0; i < 2; i++)
#pragma unroll
        for (int j = 0; j < 2; j++)
          acc[2 + i][j] = __builtin_amdgcn_mfma_f32_16x16x32_bf16(aF[i][s], bF[0][j][s], acc[2 + i][j], 0, 0, 0);
    __builtin_amdgcn_s_setprio(0);
    __builtin_amdgcn_s_barrier();
    __builtin_amdgcn_s_setprio(1);
#pragma unroll
    for (int s = 0; s < 2; s++)
#pragma unroll
      for (int i = 0; i < 2; i++)
#pragma unroll
        for (int j = 0; j < 2; j++)
          acc[2 + i][2 + j] = __builtin_amdgcn_mfma_f32_16x16x32_bf16(aF[i][s], bF[1][j][s], acc[2 + i][2 + j], 0, 0, 0);
    __builtin_amdgcn_s_setprio(0);
    if (st) asm volatile("s_waitcnt vmcnt(6)" ::: "memory");
    else    asm volatile("s_waitcnt vmcnt(0)" ::: "memory");
    __builtin_amdgcn_s_barrier();
  }

  const int m0 = bm * 256 + wr * 64;
  const int n0 = bn * 128 + wc * 64;
  const int rsub = (l >> 4) * 4;
  const int ccol = l & 15;
#pragma unroll
  for (int i = 0; i < 4; i++) {
#pragma unroll
    for (int j = 0; j < 4; j++) {
      int n = n0 + j * 16 + ccol;
#pragma unroll
      for (int tt = 0; tt < 4; tt++) {
        int m = m0 + i * 16 + rsub + tt;
        float v = acc[i][j][tt];
        size_t idx = (size_t)m * N + n;
        if constexpr (EPI == 0) {
          float sv = v / (1.f + __expf(-v));
          Cbf[(size_t)bz * sC + idx] = f2bf(sv);
        } else if constexpr (EPI == 1) {
          float sc = v * 0.08838834764831845f;
          sc = sc > 0.f ? sc * sc : 0.f;
          Cbf[(size_t)bz * sC + idx] = f2bf(sc);
        } else if constexpr (EPI == 2) {
          float uvl = bf2f(U[(size_t)m * ldu + n]);
          Cbf[(size_t)bz * sC + idx] = f2bf(v * uvl);
        } else {
          Cf[idx] = Xres[idx] * rscale[n] + v;
        }
      }
    }
  }
}

// ---------------- legacy 128x128 GEMM (fallback path only) ----------------
template <int EPI>
__global__ __launch_bounds__(256) void gemm_bt(
    const u16* __restrict__ A, const u16* __restrict__ B,
    int M, int N, int K,
    u16* __restrict__ Cbf, float* __restrict__ Cf,
    const u16* __restrict__ U, int ldu,
    const float* __restrict__ Xres, const float* __restrict__ rscale,
    size_t sA, size_t sB, size_t sC, size_t sU) {
  __shared__ u16 As[128 * 32];
  __shared__ u16 Bs[128 * 32];
  const int tid = threadIdx.x;
  const int wave = tid >> 6, lane = tid & 63;
  const int wr = wave >> 1, wc = wave & 1;
  const int bz = blockIdx.z;
  A += (size_t)bz * sA; B += (size_t)bz * sB; U += (size_t)bz * sU;
  const int nbx = gridDim.x;
  int li = blockIdx.y * nbx + blockIdx.x;
  const int cpx = (nbx * gridDim.y) >> 3;
  li = (li & 7) * cpx + (li >> 3);
  const int bn = li % nbx;
  const int bm = li / nbx;
  const size_t abase = (size_t)bm * 128 * K;
  const size_t bbase = (size_t)bn * 128 * K;
  const int srow = tid >> 2;
  const int scol = (tid & 3) * 8;
  f32x4 acc[4][4];
#pragma unroll
  for (int i = 0; i < 4; i++)
#pragma unroll
    for (int j = 0; j < 4; j++) acc[i][j] = f32x4{0.f, 0.f, 0.f, 0.f};
  const int fr = lane & 15;
  const int fk = (lane >> 4) * 8;
  for (int k0 = 0; k0 < K; k0 += 32) {
#pragma unroll
    for (int r = 0; r < 2; r++) {
      const u16* gA = A + abase + (size_t)(r * 64 + srow) * K + k0 + scol;
      const u16* gB = B + bbase + (size_t)(r * 64 + srow) * K + k0 + scol;
      gload16(gA, As + r * 2048 + wave * 512);
      gload16(gB, Bs + r * 2048 + wave * 512);
    }
    __syncthreads();
    bf16x8 af[4], bfr[4];
#pragma unroll
    for (int i = 0; i < 4; i++) {
      af[i]  = *reinterpret_cast<const bf16x8*>(&As[(wr * 64 + i * 16 + fr) * 32 + fk]);
      bfr[i] = *reinterpret_cast<const bf16x8*>(&Bs[(wc * 64 + i * 16 + fr) * 32 + fk]);
    }
#pragma unroll
    for (int i = 0; i < 4; i++)
#pragma unroll
      for (int j = 0; j < 4; j++)
        acc[i][j] = __builtin_amdgcn_mfma_f32_16x16x32_bf16(af[i], bfr[j], acc[i][j], 0, 0, 0);
    __syncthreads();
  }
  const int m0 = bm * 128 + wr * 64;
  const int n0 = bn * 128 + wc * 64;
  const int rsub = (lane >> 4) * 4;
  const int ccol = lane & 15;
#pragma unroll
  for (int i = 0; i < 4; i++) {
#pragma unroll
    for (int j = 0; j < 4; j++) {
      int n = n0 + j * 16 + ccol;
#pragma unroll
      for (int t = 0; t < 4; t++) {
        int m = m0 + i * 16 + rsub + t;
        float v = acc[i][j][t];
        size_t idx = (size_t)m * N + n;
        if constexpr (EPI == 0) {
          float sv = v / (1.f + __expf(-v));
          Cbf[(size_t)bz * sC + idx] = f2bf(sv);
        } else if constexpr (EPI == 1) {
          float sc = v * 0.08838834764831845f;
          sc = sc > 0.f ? sc * sc : 0.f;
          Cbf[(size_t)bz * sC + idx] = f2bf(sc);
        } else if constexpr (EPI == 2) {
          float uvl = bf2f(U[(size_t)m * ldu + n]);
          Cbf[(size_t)bz * sC + idx] = f2bf(v * uvl);
        } else {
          Cf[idx] = Xres[idx] * rscale[n] + v;
        }
      }
    }
  }
}

// ---------------- launcher ----------------

extern "C" void kernel_launch(void* const* d_in, const int* in_sizes, int n_in,
                              void* d_out, int out_size, void* d_ws, size_t ws_size,
                              hipStream_t stream) {
  const float* x        = (const float*)d_in[0];
  const float* pos_enc  = (const float*)d_in[1];
  const float* uv_w     = (const float*)d_in[2];
  const float* o_w      = (const float*)d_in[3];
  const float* gamma    = (const float*)d_in[4];
  const float* beta     = (const float*)d_in[5];
  const float* ln_g     = (const float*)d_in[6];
  const float* res_scale= (const float*)d_in[7];
  float* out = (float*)d_out;

  auto al = [](size_t b) { return (b + 255) & ~(size_t)255; };
  const size_t SZ_UVW  = (size_t)FDIM * DDIM * 2;
  const size_t SZ_OW   = (size_t)DDIM * EDIM * 2;
  const size_t SZ_Z    = (size_t)NBATCH * SEQ * EDIM * 2;
  const size_t SZ_XN   = (size_t)NBATCH * SEQ * DDIM * 2;
  const size_t SZ_UV   = (size_t)NBATCH * SEQ * FDIM * 2;
  const size_t SZ_QK   = (size_t)NBATCH * SEQ * SATT * 2;
  const size_t SZ_VT1  = (size_t)EDIM * SEQ * 2;
  const size_t SZ_P1   = (size_t)SEQ * SEQ * 2;
  const size_t need_full =
      al(SZ_UVW) + al(SZ_OW) + al(SZ_Z) + al(SZ_XN) + al(SZ_UV) + 2 * al(SZ_QK) +
      (size_t)NBATCH * (al(SZ_VT1) + al(SZ_P1));
  const bool FULL = ws_size >= need_full;

  char* p = (char*)d_ws;
  auto alloc = [&](size_t bytes) {
    char* r = p;
    p += (bytes + 255) & ~(size_t)255;
    return r;
  };

  if (FULL) {
    u16* uvw_bf = (u16*)alloc(SZ_UVW);
    u16* ow_bf  = (u16*)alloc(SZ_OW);
    u16* z      = (u16*)alloc(SZ_Z);
    u16* vt     = (u16*)alloc((size_t)NBATCH * al(SZ_VT1));
    u16* pmat   = (u16*)alloc((size_t)NBATCH * al(SZ_P1));
    u16* xn     = (u16*)alloc(SZ_XN);
    u16* uv     = (u16*)alloc(SZ_UV);
    u16* qb     = (u16*)alloc(SZ_QK);
    u16* kb     = (u16*)alloc(SZ_QK);
    const size_t sVT = al(SZ_VT1) >> 1;
    const size_t sP  = al(SZ_P1) >> 1;
    const int rows = NBATCH * SEQ;  // 8192

    cvt_bf16_kernel<<<(FDIM * DDIM / 4 + 255) / 256, 256, 0, stream>>>(
        uv_w, uvw_bf, FDIM * DDIM / 4);
    cvt_bf16_kernel<<<(DDIM * EDIM / 4 + 255) / 256, 256, 0, stream>>>(
        o_w, ow_bf, DDIM * EDIM / 4);

    rms_kernel<<<rows, 256, 0, stream>>>(x, ln_g, xn);
    // gemm0: 17 col-tiles, last one ragged (128 wide, fuses q/k) -> 544 blocks
    gemm_bt3<0><<<dim3(17, rows / 256), 512, 0, stream>>>(
        xn, uvw_bf, FDIM, DDIM, uv, nullptr, 0,
        pos_enc, gamma, beta, qb, kb, 0, 0, 0, 0);
    transpose_v<<<dim3(EDIM / 64, SEQ / 64, NBATCH), 256, 0, stream>>>(uv, vt, FDIM);
    gemm_bt3<1><<<dim3(SEQ / 256, SEQ / 256, NBATCH), 512, 0, stream>>>(
        qb, kb, SEQ, SATT, pmat, nullptr, 0,
        nullptr, nullptr, nullptr, nullptr, nullptr,
        (size_t)SEQ * SATT, (size_t)SEQ * SATT, sP, 0);
    gemm_bt3<2><<<dim3(EDIM / 256, SEQ / 256, NBATCH), 512, 0, stream>>>(
        pmat, vt, EDIM, SEQ, z, uv, FDIM,
        nullptr, nullptr, nullptr, nullptr, nullptr,
        sP, sVT, (size_t)SEQ * EDIM, (size_t)SEQ * FDIM);
    gemm_bt2<3><<<dim3(DDIM / 128, rows / 256), 512, 0, stream>>>(
        z, ow_bf, rows, DDIM, EDIM, nullptr, out, nullptr, 0,
        x, res_scale, 0, 0, 0, 0);
    return;
  }

  // ---------- fallback (small workspace): round-2 structure ----------
  u16* uvw_bf = (u16*)alloc(SZ_UVW);
  u16* ow_bf  = (u16*)alloc(SZ_OW);
  u16* z      = (u16*)alloc(SZ_Z);
  u16* vt     = (u16*)alloc(SZ_VT1);
  u16* pmat   = (u16*)alloc(SZ_P1);
  size_t fixed = (size_t)(p - (char*)d_ws);
  const size_t perbc = (size_t)SEQ * DDIM * 2 + (size_t)SEQ * FDIM * 2 +
                       2 * (size_t)SEQ * SATT * 2 + 4 * 256;
  int BC = (ws_size >= fixed + 4 * perbc) ? 4 : 1;
  u16* xn = (u16*)alloc((size_t)BC * SEQ * DDIM * 2);
  u16* uv = (u16*)alloc((size_t)BC * SEQ * FDIM * 2);
  u16* qb = (u16*)alloc((size_t)BC * SEQ * SATT * 2);
  u16* kb = (u16*)alloc((size_t)BC * SEQ * SATT * 2);

  cvt_bf16_kernel<<<(FDIM * DDIM / 4 + 255) / 256, 256, 0, stream>>>(
      uv_w, uvw_bf, FDIM * DDIM / 4);
  cvt_bf16_kernel<<<(DDIM * EDIM / 4 + 255) / 256, 256, 0, stream>>>(
      o_w, ow_bf, DDIM * EDIM / 4);

  for (int b0 = 0; b0 < NBATCH; b0 += BC) {
    int rows = BC * SEQ;
    rms_kernel<<<rows, 256, 0, stream>>>(x + (size_t)b0 * SEQ * DDIM, ln_g, xn);
    gemm_bt<0><<<dim3(FDIM / 128, rows / 128), 256, 0, stream>>>(
        xn, uvw_bf, rows, FDIM, DDIM, uv, nullptr, nullptr, 0, nullptr, nullptr,
        0, 0, 0, 0);
    qk_kernel<<<rows, SATT, 0, stream>>>(uv, pos_enc, gamma, beta, qb, kb, FDIM);
    for (int bb = 0; bb < BC; bb++) {
      int b = b0 + bb;
      const u16* uvb = uv + (size_t)bb * SEQ * FDIM;
      transpose_v<<<dim3(EDIM / 64, SEQ / 64, 1), 256, 0, stream>>>(uvb, vt, FDIM);
      gemm_bt<1><<<dim3(SEQ / 128, SEQ / 128), 256, 0, stream>>>(
          qb + (size_t)bb * SEQ * SATT, kb + (size_t)bb * SEQ * SATT,
          SEQ, SEQ, SATT, pmat, nullptr, nullptr, 0, nullptr, nullptr,
          0, 0, 0, 0);
      gemm_bt<2><<<dim3(EDIM / 128, SEQ / 128), 256, 0, stream>>>(
          pmat, vt, SEQ, EDIM, SEQ, z + (size_t)b * SEQ * EDIM, nullptr,
          uvb, FDIM, nullptr, nullptr, 0, 0, 0, 0);
    }
  }
  gemm_bt<3><<<dim3(DDIM / 128, (NBATCH * SEQ) / 128), 256, 0, stream>>>(
      z, ow_bf, NBATCH * SEQ, DDIM, EDIM, nullptr, out, nullptr, 0,
      x, res_scale, 0, 0, 0, 0);
}

// Round 16
// 273.024 us; speedup vs baseline: 1.0631x; 1.0631x over previous
//
#include <hip/hip_runtime.h>

typedef unsigned short u16;
typedef __bf16 bf16x8 __attribute__((ext_vector_type(8)));
typedef float f32x4 __attribute__((ext_vector_type(4)));

#define SEQ   2048
#define DDIM  1024
#define EDIM  2048
#define FDIM  4224   /* 2E + S_ATT */
#define SATT  128
#define NBATCH 4

__device__ __forceinline__ u16 f2bf(float f) {
  unsigned u = __float_as_uint(f);
  unsigned r = (u + 0x7fffu + ((u >> 16) & 1u)) >> 16;
  return (u16)r;
}
__device__ __forceinline__ float bf2f(u16 v) {
  return __uint_as_float(((unsigned)v) << 16);
}

__device__ __forceinline__ void gload16(const u16* g, u16* l) {
  auto gp = (const __attribute__((address_space(1))) u16*)(unsigned long long)g;
  auto lp = (__attribute__((address_space(3))) u16*)(unsigned)(unsigned long long)l;
  __builtin_amdgcn_global_load_lds(gp, lp, 16, 0, 0);
}

// ---------------- elementwise / small kernels ----------------

__global__ void cvt_bf16_kernel(const float* __restrict__ in, u16* __restrict__ out, int n4) {
  int i = blockIdx.x * blockDim.x + threadIdx.x;
  if (i >= n4) return;
  float4 v = reinterpret_cast<const float4*>(in)[i];
  unsigned p0 = (unsigned)f2bf(v.x) | ((unsigned)f2bf(v.y) << 16);
  unsigned p1 = (unsigned)f2bf(v.z) | ((unsigned)f2bf(v.w) << 16);
  uint2 pk; pk.x = p0; pk.y = p1;
  reinterpret_cast<uint2*>(out)[i] = pk;
}

__global__ void rms_kernel(const float* __restrict__ x, const float* __restrict__ ln_g,
                           u16* __restrict__ xn) {
  int row = blockIdx.x;
  int t = threadIdx.x;
  const float4* xr = reinterpret_cast<const float4*>(x + (size_t)row * DDIM);
  float4 v = xr[t];
  float s = v.x * v.x + v.y * v.y + v.z * v.z + v.w * v.w;
#pragma unroll
  for (int off = 32; off > 0; off >>= 1) s += __shfl_down(s, off);
  __shared__ float wsum[4];
  int lane = t & 63, wv = t >> 6;
  if (lane == 0) wsum[wv] = s;
  __syncthreads();
  float tot = wsum[0] + wsum[1] + wsum[2] + wsum[3];
  float rms = sqrtf(tot * (1.0f / (float)DDIM));
  float scale = ln_g[0] / fmaxf(rms, 1e-5f);
  unsigned p0 = (unsigned)f2bf(v.x * scale) | ((unsigned)f2bf(v.y * scale) << 16);
  unsigned p1 = (unsigned)f2bf(v.z * scale) | ((unsigned)f2bf(v.w * scale) << 16);
  uint2 pk; pk.x = p0; pk.y = p1;
  reinterpret_cast<uint2*>(xn + (size_t)row * DDIM)[t] = pk;
}

__global__ void qk_kernel(const u16* __restrict__ uv, const float* __restrict__ pos_enc,
                          const float* __restrict__ gamma, const float* __restrict__ beta,
                          u16* __restrict__ q, u16* __restrict__ k, int ldF) {
  int r = blockIdx.x;
  int t = threadIdx.x;
  int s = r & (SEQ - 1);
  float bval = bf2f(uv[(size_t)r * ldF + 2 * EDIM + t]);
  float pe = pos_enc[(size_t)s * SATT + t];
  float qv = bval * gamma[t] + beta[t] + pe;
  float kv = bval * gamma[SATT + t] + beta[SATT + t] + pe;
  q[(size_t)r * SATT + t] = f2bf(qv);
  k[(size_t)r * SATT + t] = f2bf(kv);
}

// vt[b][e][s] = uv[b][s][E + e] -- 64x64 tiles, 256 thr, 16 u16/thread.
// LDS pad 68: row stride 136 B (8B-aligned for uint2; 2-way bank alias on
// column reads = free per m136). Verified correct in R15.
__global__ void transpose_v(const u16* __restrict__ uv, u16* __restrict__ vt, int ldF) {
  __shared__ u16 tile[64][68];
  int b = blockIdx.z;
  uv += (size_t)b * SEQ * ldF;
  vt += (size_t)b * EDIM * SEQ;
  int e0 = blockIdx.x * 64, s0 = blockIdx.y * 64;
  int t = threadIdx.x;
  int r = t >> 2;            // 0..63
  int c = (t & 3) << 4;      // 0,16,32,48
  const u16* src = uv + (size_t)(s0 + r) * ldF + EDIM + e0 + c;
#pragma unroll
  for (int p = 0; p < 4; p++)
    *reinterpret_cast<uint2*>(&tile[r][c + p * 4]) =
        *reinterpret_cast<const uint2*>(src + p * 4);
  __syncthreads();
  u16 buf[16];
#pragma unroll
  for (int j = 0; j < 16; j++) buf[j] = tile[c + j][r];
  u16* dst = vt + (size_t)(e0 + r) * SEQ + s0 + c;
#pragma unroll
  for (int p = 0; p < 4; p++)
    *reinterpret_cast<uint2*>(dst + p * 4) = *reinterpret_cast<uint2*>(&buf[p * 4]);
}

// ======== GEMM v4 (R8 verbatim: single-barrier tile, compiler-scheduled) ===
// C = A(M,K)*B(N,K)^T. BM=BN=256 (last col-tile may be ragged 128), BK=64,
// 512 thr = 8 waves (2 wm x 4 wn), per-wave 128x64.
// LDS 128 KiB = 2 dbuf x 4 panels of 16 KiB. Classic double buffer; at tile
// t top stage t+1 -> buf^1, then all ds_reads + MFMAs compiler-scheduled;
// boundary = vmcnt(0) + s_barrier + sched_barrier(0). XOR swizzle
// byte^=(row&7)<<4 on ds_read; inverse pre-applied to global staging source.
template <int EPI>
__global__ __launch_bounds__(512, 2) void gemm_bt3(
    const u16* __restrict__ A, const u16* __restrict__ B,
    int N, int K,
    u16* __restrict__ Cbf,
    const u16* __restrict__ U, int ldu,
    size_t sA, size_t sB, size_t sC, size_t sU) {
  __shared__ u16 lds[65536];  // 128 KiB
  const int tid = threadIdx.x;
  const int w = tid >> 6, l = tid & 63;
  const int wm2 = w >> 2, wn2 = w & 3;
  const int fr = l & 15, kg = l >> 4;

  const int bz = blockIdx.z;
  A += (size_t)bz * sA; B += (size_t)bz * sB; U += (size_t)bz * sU;

  // XCD-aware bijective swizzle (nwg % 8 == 0 for all launched shapes)
  const int nbx = gridDim.x;
  int li = blockIdx.y * nbx + blockIdx.x;
  const int cpx = (nbx * gridDim.y) >> 3;
  li = (li & 7) * cpx + (li >> 3);
  const int bn = li % nbx;
  const int bm = li / nbx;

  const int NT = K >> 6;                     // even for all callers
  const bool full = (bn * 256 + 256 <= N);   // block-uniform ragged flag

  const int r0 = (w << 3) + (l >> 3);                  // staging row 0..63
  const int cswz = (((l & 7) ^ (l >> 3)) & 7) << 3;    // inv-swizzled col

  // staging pointers: 4 panels x 2 row-groups; advance 128 elems / 2 tiles
  const u16* pA00 = A + (size_t)bm * 256 * K + (size_t)r0 * K + cswz;
  const u16* pA01 = pA00 + (size_t)64 * K;
  const u16* pA10 = pA00 + (size_t)128 * K;
  const u16* pA11 = pA00 + (size_t)192 * K;
  const u16* pB00 = B + (size_t)bn * 256 * K + (size_t)r0 * K + cswz;
  const u16* pB01 = pB00 + (size_t)64 * K;
  const u16* pB10 = pB00 + (size_t)128 * K;
  const u16* pB11 = pB00 + (size_t)192 * K;

  // precomputed swizzled LDS read bases
  const int X  = (l & 7) << 4;
  const int Y0 = (kg << 4) ^ X;
  const int Y1 = ((kg << 4) | 64) ^ X;
  const char* ldsC = (const char*)lds;
  const char* aR0 = ldsC + wm2 * 8192 + fr * 128 + Y0;
  const char* aR1 = ldsC + wm2 * 8192 + fr * 128 + Y1;
  const char* bR0 = ldsC + 32768 + wn2 * 4096 + fr * 128 + Y0;
  const char* bR1 = ldsC + 32768 + wn2 * 4096 + fr * 128 + Y1;

  // LDS stage destination: word off = buf*32768 + p*8192 + w*512 (+4096 L1)
  auto stg = [&](int bufw, int p, const u16* g0, const u16* g1, int ofs) {
    u16* d = lds + bufw * 32768 + p * 8192 + w * 512;
    gload16(g0 + ofs, d);
    gload16(g1 + ofs, d + 4096);
  };

  f32x4 acc[8][4];
#pragma unroll
  for (int i = 0; i < 8; i++)
#pragma unroll
    for (int j = 0; j < 4; j++) acc[i][j] = f32x4{0.f, 0.f, 0.f, 0.f};

  // prologue: stage tile 0 -> buf0; drain; barrier
  stg(0, 0, pA00, pA01, 0); stg(0, 2, pB00, pB01, 0);
  if (full) stg(0, 3, pB10, pB11, 0);
  stg(0, 1, pA10, pA11, 0);
  asm volatile("s_waitcnt vmcnt(0)" ::: "memory");
  __builtin_amdgcn_s_barrier();
  __builtin_amdgcn_sched_barrier(0);

  bf16x8 aH[4][2], bF[2][2][2];  // bF[qb][j][s]

#define MFMA_Q(QA, QB)                                                        \
  _Pragma("unroll") for (int s = 0; s < 2; s++)                               \
  _Pragma("unroll") for (int i = 0; i < 4; i++)                               \
  _Pragma("unroll") for (int j = 0; j < 2; j++)                               \
    acc[(QA)*4 + i][(QB)*2 + j] = __builtin_amdgcn_mfma_f32_16x16x32_bf16(    \
        aH[i][s], bF[QB][j][s], acc[(QA)*4 + i][(QB)*2 + j], 0, 0, 0);

#define TILE_STEP(BUF, ST, OFS)                                               \
  {                                                                           \
    if (ST) {                                                                 \
      stg((BUF) ^ 1, 0, pA00, pA01, OFS);                                     \
      stg((BUF) ^ 1, 2, pB00, pB01, OFS);                                     \
      if (full) stg((BUF) ^ 1, 3, pB10, pB11, OFS);                           \
      stg((BUF) ^ 1, 1, pA10, pA11, OFS);                                     \
    }                                                                         \
    _Pragma("unroll") for (int i = 0; i < 4; i++) {                           \
      aH[i][0] = *(const bf16x8*)(aR0 + (BUF) * 65536 + i * 2048);            \
      aH[i][1] = *(const bf16x8*)(aR1 + (BUF) * 65536 + i * 2048);            \
    }                                                                         \
    _Pragma("unroll") for (int j = 0; j < 2; j++) {                           \
      bF[0][j][0] = *(const bf16x8*)(bR0 + (BUF) * 65536 + j * 2048);         \
      bF[0][j][1] = *(const bf16x8*)(bR1 + (BUF) * 65536 + j * 2048);         \
    }                                                                         \
    MFMA_Q(0, 0)                                                              \
    if (full) {                                                               \
      _Pragma("unroll") for (int j = 0; j < 2; j++) {                         \
        bF[1][j][0] = *(const bf16x8*)(bR0 + (BUF) * 65536 + 16384 + j * 2048);\
        bF[1][j][1] = *(const bf16x8*)(bR1 + (BUF) * 65536 + 16384 + j * 2048);\
      }                                                                       \
      MFMA_Q(0, 1)                                                            \
    }                                                                         \
    _Pragma("unroll") for (int i = 0; i < 4; i++) {                           \
      aH[i][0] = *(const bf16x8*)(aR0 + (BUF) * 65536 + 16384 + i * 2048);    \
      aH[i][1] = *(const bf16x8*)(aR1 + (BUF) * 65536 + 16384 + i * 2048);    \
    }                                                                         \
    MFMA_Q(1, 0)                                                              \
    if (full) { MFMA_Q(1, 1) }                                                \
    asm volatile("s_waitcnt vmcnt(0)" ::: "memory");                          \
    __builtin_amdgcn_s_barrier();                                             \
    __builtin_amdgcn_sched_barrier(0);                                        \
  }

  for (int t2 = 0; t2 < NT; t2 += 2) {
    const bool st0 = (t2 + 1 < NT);
    const bool st1 = (t2 + 2 < NT);
    TILE_STEP(0, st0, 64)
    TILE_STEP(1, st1, 128)
    pA00 += 128; pA01 += 128; pA10 += 128; pA11 += 128;
    pB00 += 128; pB01 += 128; pB10 += 128; pB11 += 128;
  }
#undef TILE_STEP
#undef MFMA_Q

  // epilogue
  const int rsub = (l >> 4) * 4;
  const int ccol = l & 15;
#pragma unroll
  for (int ai = 0; ai < 8; ai++) {
#pragma unroll
    for (int bj = 0; bj < 4; bj++) {
      if (!full && bj >= 2) continue;
      int n = bn * 256 + (bj >> 1) * 128 + wn2 * 32 + (bj & 1) * 16 + ccol;
#pragma unroll
      for (int tt = 0; tt < 4; tt++) {
        int m = bm * 256 + (ai >> 2) * 128 + wm2 * 64 + (ai & 3) * 16 + rsub + tt;
        float v = acc[ai][bj][tt];
        size_t idx = (size_t)m * N + n;
        if constexpr (EPI == 0) {
          float sv = v / (1.f + __expf(-v));
          Cbf[(size_t)bz * sC + idx] = f2bf(sv);
        } else if constexpr (EPI == 1) {
          float sc = v * 0.08838834764831845f;  // 1/sqrt(128)
          sc = sc > 0.f ? sc * sc : 0.f;
          Cbf[(size_t)bz * sC + idx] = f2bf(sc);
        } else {
          float uvl = bf2f(U[(size_t)m * ldu + n]);
          Cbf[(size_t)bz * sC + idx] = f2bf(v * uvl);
        }
      }
    }
  }
}

// ======== 256x128 deep-pipeline GEMM (gemm3; round-3 proven) ====
template <int EPI>
__global__ __launch_bounds__(512, 2) void gemm_bt2(
    const u16* __restrict__ A, const u16* __restrict__ B,
    int M, int N, int K,
    u16* __restrict__ Cbf, float* __restrict__ Cf,
    const u16* __restrict__ U, int ldu,
    const float* __restrict__ Xres, const float* __restrict__ rscale,
    size_t sA, size_t sB, size_t sC, size_t sU) {
  __shared__ u16 lds[3 * 24576];  // 144 KiB
  const int tid = threadIdx.x;
  const int w = tid >> 6, l = tid & 63;
  const int wr = w >> 1, wc = w & 1;
  const int fr = l & 15, kg = l >> 4;

  const int bz = blockIdx.z;
  A += (size_t)bz * sA; B += (size_t)bz * sB; U += (size_t)bz * sU;

  const int nbx = gridDim.x;
  int li = blockIdx.y * nbx + blockIdx.x;
  const int cpx = (nbx * gridDim.y) >> 3;
  li = (li & 7) * cpx + (li >> 3);
  const int bn = li % nbx;
  const int bm = li / nbx;

  const int NT = K >> 6;
  const int srow = (w << 3) + (l >> 3);
  const int scol = (((l & 7) ^ (l >> 3)) & 7) << 3;
  const size_t aoff = (size_t)bm * 256 * K;
  const size_t boff = (size_t)bn * 128 * K;
  const char* ldsC = (const char*)lds;

  auto stageAu = [&](int t, int h) {
    int sb = (t % 3) * 24576 + h * 8192;
    const u16* g = A + aoff + (size_t)(h * 128 + srow) * K + t * 64 + scol;
#pragma unroll
    for (int L = 0; L < 2; L++)
      gload16(g + (size_t)(L * 64) * K, &lds[sb + (L * 8 + w) * 512]);
  };
  auto stageBu = [&](int t) {
    int sb = (t % 3) * 24576 + 16384;
    const u16* g = B + boff + (size_t)srow * K + t * 64 + scol;
#pragma unroll
    for (int L = 0; L < 2; L++)
      gload16(g + (size_t)(L * 64) * K, &lds[sb + (L * 8 + w) * 512]);
  };
  auto ldA = [&](int cur, int i, int s) -> bf16x8 {
    int r = ((wr & 1) << 6) + (i << 4) + fr;
    int off = cur * 49152 + ((wr >> 1) << 14) + (r << 7) + (s << 6) + (kg << 4);
    off ^= (r & 7) << 4;
    return *(const bf16x8*)(ldsC + off);
  };
  auto ldB = [&](int cur, int j, int s) -> bf16x8 {
    int r = (wc << 6) + (j << 4) + fr;
    int off = cur * 49152 + 32768 + (r << 7) + (s << 6) + (kg << 4);
    off ^= (r & 7) << 4;
    return *(const bf16x8*)(ldsC + off);
  };

  f32x4 acc[4][4];
#pragma unroll
  for (int i = 0; i < 4; i++)
#pragma unroll
    for (int j = 0; j < 4; j++) acc[i][j] = f32x4{0.f, 0.f, 0.f, 0.f};

  stageAu(0, 0); stageAu(0, 1); stageBu(0);
  if (NT > 1) { stageAu(1, 0); stageAu(1, 1); stageBu(1); }
  asm volatile("s_waitcnt vmcnt(6)" ::: "memory");
  __builtin_amdgcn_s_barrier();

  bf16x8 aF[2][2], bF[2][2][2];
  for (int t = 0; t < NT; ++t) {
    const int cur = t % 3;
    const bool st = (t + 2 < NT);
#pragma unroll
    for (int i = 0; i < 2; i++)
#pragma unroll
      for (int s = 0; s < 2; s++) aF[i][s] = ldA(cur, i, s);
#pragma unroll
    for (int j = 0; j < 2; j++)
#pragma unroll
      for (int s = 0; s < 2; s++) bF[0][j][s] = ldB(cur, j, s);
    if (st) stageAu(t + 2, 0);
    __builtin_amdgcn_s_barrier();
    __builtin_amdgcn_s_setprio(1);
#pragma unroll
    for (int s = 0; s < 2; s++)
#pragma unroll
      for (int i = 0; i < 2; i++)
#pragma unroll
        for (int j = 0; j < 2; j++)
          acc[i][j] = __builtin_amdgcn_mfma_f32_16x16x32_bf16(aF[i][s], bF[0][j][s], acc[i][j], 0, 0, 0);
    __builtin_amdgcn_s_setprio(0);
    __builtin_amdgcn_s_barrier();
#pragma unroll
    for (int j = 0; j < 2; j++)
#pragma unroll
      for (int s = 0; s < 2; s++) bF[1][j][s] = ldB(cur, 2 + j, s);
    if (st) stageAu(t + 2, 1);
    __builtin_amdgcn_s_barrier();
    __builtin_amdgcn_s_setprio(1);
#pragma unroll
    for (int s = 0; s < 2; s++)
#pragma unroll
      for (int i = 0; i < 2; i++)
#pragma unroll
        for (int j = 0; j < 2; j++)
          acc[i][2 + j] = __builtin_amdgcn_mfma_f32_16x16x32_bf16(aF[i][s], bF[1][j][s], acc[i][2 + j], 0, 0, 0);
    __builtin_amdgcn_s_setprio(0);
    __builtin_amdgcn_s_barrier();
#pragma unroll
    for (int i = 0; i < 2; i++)
#pragma unroll
      for (int s = 0; s < 2; s++) aF[i][s] = ldA(cur, 2 + i, s);
    if (st) stageBu(t + 2);
    __builtin_amdgcn_s_barrier();
    __builtin_amdgcn_s_setprio(1);
#pragma unroll
    for (int s = 0; s < 2; s++)
#pragma unroll
      for (int i = 0; i < 2; i++)
#pragma unroll
        for (int j = 0; j < 2; j++)
          acc[2 + i][j] = __builtin_amdgcn_mfma_f32_16x16x32_bf16(aF[i][s], bF[0][j][s], acc[2 + i][j], 0, 0, 0);
    __builtin_amdgcn_s_setprio(0);
    __builtin_amdgcn_s_barrier();
    __builtin_amdgcn_s_setprio(1);
#pragma unroll
    for (int s = 0; s < 2; s++)
#pragma unroll
      for (int i = 0; i < 2; i++)
#pragma unroll
        for (int j = 0; j < 2; j++)
          acc[2 + i][2 + j] = __builtin_amdgcn_mfma_f32_16x16x32_bf16(aF[i][s], bF[1][j][s], acc[2 + i][2 + j], 0, 0, 0);
    __builtin_amdgcn_s_setprio(0);
    if (st) asm volatile("s_waitcnt vmcnt(6)" ::: "memory");
    else    asm volatile("s_waitcnt vmcnt(0)" ::: "memory");
    __builtin_amdgcn_s_barrier();
  }

  const int m0 = bm * 256 + wr * 64;
  const int n0 = bn * 128 + wc * 64;
  const int rsub = (l >> 4) * 4;
  const int ccol = l & 15;
#pragma unroll
  for (int i = 0; i < 4; i++) {
#pragma unroll
    for (int j = 0; j < 4; j++) {
      int n = n0 + j * 16 + ccol;
#pragma unroll
      for (int tt = 0; tt < 4; tt++) {
        int m = m0 + i * 16 + rsub + tt;
        float v = acc[i][j][tt];
        size_t idx = (size_t)m * N + n;
        if constexpr (EPI == 0) {
          float sv = v / (1.f + __expf(-v));
          Cbf[(size_t)bz * sC + idx] = f2bf(sv);
        } else if constexpr (EPI == 1) {
          float sc = v * 0.08838834764831845f;
          sc = sc > 0.f ? sc * sc : 0.f;
          Cbf[(size_t)bz * sC + idx] = f2bf(sc);
        } else if constexpr (EPI == 2) {
          float uvl = bf2f(U[(size_t)m * ldu + n]);
          Cbf[(size_t)bz * sC + idx] = f2bf(v * uvl);
        } else {
          Cf[idx] = Xres[idx] * rscale[n] + v;
        }
      }
    }
  }
}

// ---------------- legacy 128x128 GEMM (fallback path only) ----------------
template <int EPI>
__global__ __launch_bounds__(256) void gemm_bt(
    const u16* __restrict__ A, const u16* __restrict__ B,
    int M, int N, int K,
    u16* __restrict__ Cbf, float* __restrict__ Cf,
    const u16* __restrict__ U, int ldu,
    const float* __restrict__ Xres, const float* __restrict__ rscale,
    size_t sA, size_t sB, size_t sC, size_t sU) {
  __shared__ u16 As[128 * 32];
  __shared__ u16 Bs[128 * 32];
  const int tid = threadIdx.x;
  const int wave = tid >> 6, lane = tid & 63;
  const int wr = wave >> 1, wc = wave & 1;
  const int bz = blockIdx.z;
  A += (size_t)bz * sA; B += (size_t)bz * sB; U += (size_t)bz * sU;
  const int nbx = gridDim.x;
  int li = blockIdx.y * nbx + blockIdx.x;
  const int cpx = (nbx * gridDim.y) >> 3;
  li = (li & 7) * cpx + (li >> 3);
  const int bn = li % nbx;
  const int bm = li / nbx;
  const size_t abase = (size_t)bm * 128 * K;
  const size_t bbase = (size_t)bn * 128 * K;
  const int srow = tid >> 2;
  const int scol = (tid & 3) * 8;
  f32x4 acc[4][4];
#pragma unroll
  for (int i = 0; i < 4; i++)
#pragma unroll
    for (int j = 0; j < 4; j++) acc[i][j] = f32x4{0.f, 0.f, 0.f, 0.f};
  const int fr = lane & 15;
  const int fk = (lane >> 4) * 8;
  for (int k0 = 0; k0 < K; k0 += 32) {
#pragma unroll
    for (int r = 0; r < 2; r++) {
      const u16* gA = A + abase + (size_t)(r * 64 + srow) * K + k0 + scol;
      const u16* gB = B + bbase + (size_t)(r * 64 + srow) * K + k0 + scol;
      gload16(gA, As + r * 2048 + wave * 512);
      gload16(gB, Bs + r * 2048 + wave * 512);
    }
    __syncthreads();
    bf16x8 af[4], bfr[4];
#pragma unroll
    for (int i = 0; i < 4; i++) {
      af[i]  = *reinterpret_cast<const bf16x8*>(&As[(wr * 64 + i * 16 + fr) * 32 + fk]);
      bfr[i] = *reinterpret_cast<const bf16x8*>(&Bs[(wc * 64 + i * 16 + fr) * 32 + fk]);
    }
#pragma unroll
    for (int i = 0; i < 4; i++)
#pragma unroll
      for (int j = 0; j < 4; j++)
        acc[i][j] = __builtin_amdgcn_mfma_f32_16x16x32_bf16(af[i], bfr[j], acc[i][j], 0, 0, 0);
    __syncthreads();
  }
  const int m0 = bm * 128 + wr * 64;
  const int n0 = bn * 128 + wc * 64;
  const int rsub = (lane >> 4) * 4;
  const int ccol = lane & 15;
#pragma unroll
  for (int i = 0; i < 4; i++) {
#pragma unroll
    for (int j = 0; j < 4; j++) {
      int n = n0 + j * 16 + ccol;
#pragma unroll
      for (int t = 0; t < 4; t++) {
        int m = m0 + i * 16 + rsub + t;
        float v = acc[i][j][t];
        size_t idx = (size_t)m * N + n;
        if constexpr (EPI == 0) {
          float sv = v / (1.f + __expf(-v));
          Cbf[(size_t)bz * sC + idx] = f2bf(sv);
        } else if constexpr (EPI == 1) {
          float sc = v * 0.08838834764831845f;
          sc = sc > 0.f ? sc * sc : 0.f;
          Cbf[(size_t)bz * sC + idx] = f2bf(sc);
        } else if constexpr (EPI == 2) {
          float uvl = bf2f(U[(size_t)m * ldu + n]);
          Cbf[(size_t)bz * sC + idx] = f2bf(v * uvl);
        } else {
          Cf[idx] = Xres[idx] * rscale[n] + v;
        }
      }
    }
  }
}

// ---------------- launcher ----------------

extern "C" void kernel_launch(void* const* d_in, const int* in_sizes, int n_in,
                              void* d_out, int out_size, void* d_ws, size_t ws_size,
                              hipStream_t stream) {
  const float* x        = (const float*)d_in[0];
  const float* pos_enc  = (const float*)d_in[1];
  const float* uv_w     = (const float*)d_in[2];
  const float* o_w      = (const float*)d_in[3];
  const float* gamma    = (const float*)d_in[4];
  const float* beta     = (const float*)d_in[5];
  const float* ln_g     = (const float*)d_in[6];
  const float* res_scale= (const float*)d_in[7];
  float* out = (float*)d_out;

  auto al = [](size_t b) { return (b + 255) & ~(size_t)255; };
  const size_t SZ_UVW  = (size_t)FDIM * DDIM * 2;
  const size_t SZ_OW   = (size_t)DDIM * EDIM * 2;
  const size_t SZ_Z    = (size_t)NBATCH * SEQ * EDIM * 2;
  const size_t SZ_XN   = (size_t)NBATCH * SEQ * DDIM * 2;
  const size_t SZ_UV   = (size_t)NBATCH * SEQ * FDIM * 2;
  const size_t SZ_QK   = (size_t)NBATCH * SEQ * SATT * 2;
  const size_t SZ_VT1  = (size_t)EDIM * SEQ * 2;
  const size_t SZ_P1   = (size_t)SEQ * SEQ * 2;
  const size_t need_full =
      al(SZ_UVW) + al(SZ_OW) + al(SZ_Z) + al(SZ_XN) + al(SZ_UV) + 2 * al(SZ_QK) +
      (size_t)NBATCH * (al(SZ_VT1) + al(SZ_P1));
  const bool FULL = ws_size >= need_full;

  char* p = (char*)d_ws;
  auto alloc = [&](size_t bytes) {
    char* r = p;
    p += (bytes + 255) & ~(size_t)255;
    return r;
  };

  if (FULL) {
    u16* uvw_bf = (u16*)alloc(SZ_UVW);
    u16* ow_bf  = (u16*)alloc(SZ_OW);
    u16* z      = (u16*)alloc(SZ_Z);
    u16* vt     = (u16*)alloc((size_t)NBATCH * al(SZ_VT1));
    u16* pmat   = (u16*)alloc((size_t)NBATCH * al(SZ_P1));
    u16* xn     = (u16*)alloc(SZ_XN);
    u16* uv     = (u16*)alloc(SZ_UV);
    u16* qb     = (u16*)alloc(SZ_QK);
    u16* kb     = (u16*)alloc(SZ_QK);
    const size_t sVT = al(SZ_VT1) >> 1;
    const size_t sP  = al(SZ_P1) >> 1;
    const int rows = NBATCH * SEQ;  // 8192

    cvt_bf16_kernel<<<(FDIM * DDIM / 4 + 255) / 256, 256, 0, stream>>>(
        uv_w, uvw_bf, FDIM * DDIM / 4);
    cvt_bf16_kernel<<<(DDIM * EDIM / 4 + 255) / 256, 256, 0, stream>>>(
        o_w, ow_bf, DDIM * EDIM / 4);

    rms_kernel<<<rows, 256, 0, stream>>>(x, ln_g, xn);
    // gemm0: 17 col-tiles, last one ragged (128 wide) -> 544 blocks
    gemm_bt3<0><<<dim3(17, rows / 256), 512, 0, stream>>>(
        xn, uvw_bf, FDIM, DDIM, uv, nullptr, 0, 0, 0, 0, 0);
    qk_kernel<<<rows, SATT, 0, stream>>>(uv, pos_enc, gamma, beta, qb, kb, FDIM);
    transpose_v<<<dim3(EDIM / 64, SEQ / 64, NBATCH), 256, 0, stream>>>(uv, vt, FDIM);
    gemm_bt3<1><<<dim3(SEQ / 256, SEQ / 256, NBATCH), 512, 0, stream>>>(
        qb, kb, SEQ, SATT, pmat, nullptr, 0,
        (size_t)SEQ * SATT, (size_t)SEQ * SATT, sP, 0);
    gemm_bt3<2><<<dim3(EDIM / 256, SEQ / 256, NBATCH), 512, 0, stream>>>(
        pmat, vt, EDIM, SEQ, z, uv, FDIM,
        sP, sVT, (size_t)SEQ * EDIM, (size_t)SEQ * FDIM);
    gemm_bt2<3><<<dim3(DDIM / 128, rows / 256), 512, 0, stream>>>(
        z, ow_bf, rows, DDIM, EDIM, nullptr, out, nullptr, 0,
        x, res_scale, 0, 0, 0, 0);
    return;
  }

  // ---------- fallback (small workspace): round-2 structure ----------
  u16* uvw_bf = (u16*)alloc(SZ_UVW);
  u16* ow_bf  = (u16*)alloc(SZ_OW);
  u16* z      = (u16*)alloc(SZ_Z);
  u16* vt     = (u16*)alloc(SZ_VT1);
  u16* pmat   = (u16*)alloc(SZ_P1);
  size_t fixed = (size_t)(p - (char*)d_ws);
  const size_t perbc = (size_t)SEQ * DDIM * 2 + (size_t)SEQ * FDIM * 2 +
                       2 * (size_t)SEQ * SATT * 2 + 4 * 256;
  int BC = (ws_size >= fixed + 4 * perbc) ? 4 : 1;
  u16* xn = (u16*)alloc((size_t)BC * SEQ * DDIM * 2);
  u16* uv = (u16*)alloc((size_t)BC * SEQ * FDIM * 2);
  u16* qb = (u16*)alloc((size_t)BC * SEQ * SATT * 2);
  u16* kb = (u16*)alloc((size_t)BC * SEQ * SATT * 2);

  cvt_bf16_kernel<<<(FDIM * DDIM / 4 + 255) / 256, 256, 0, stream>>>(
      uv_w, uvw_bf, FDIM * DDIM / 4);
  cvt_bf16_kernel<<<(DDIM * EDIM / 4 + 255) / 256, 256, 0, stream>>>(
      o_w, ow_bf, DDIM * EDIM / 4);

  for (int b0 = 0; b0 < NBATCH; b0 += BC) {
    int rows = BC * SEQ;
    rms_kernel<<<rows, 256, 0, stream>>>(x + (size_t)b0 * SEQ * DDIM, ln_g, xn);
    gemm_bt<0><<<dim3(FDIM / 128, rows / 128), 256, 0, stream>>>(
        xn, uvw_bf, rows, FDIM, DDIM, uv, nullptr, nullptr, 0, nullptr, nullptr,
        0, 0, 0, 0);
    qk_kernel<<<rows, SATT, 0, stream>>>(uv, pos_enc, gamma, beta, qb, kb, FDIM);
    for (int bb = 0; bb < BC; bb++) {
      int b = b0 + bb;
      const u16* uvb = uv + (size_t)bb * SEQ * FDIM;
      transpose_v<<<dim3(EDIM / 64, SEQ / 64, 1), 256, 0, stream>>>(uvb, vt, FDIM);
      gemm_bt<1><<<dim3(SEQ / 128, SEQ / 128), 256, 0, stream>>>(
          qb + (size_t)bb * SEQ * SATT, kb + (size_t)bb * SEQ * SATT,
          SEQ, SEQ, SATT, pmat, nullptr, nullptr, 0, nullptr, nullptr,
          0, 0, 0, 0);
      gemm_bt<2><<<dim3(EDIM / 128, SEQ / 128), 256, 0, stream>>>(
          pmat, vt, SEQ, EDIM, SEQ, z + (size_t)b * SEQ * EDIM, nullptr,
          uvb, FDIM, nullptr, nullptr, 0, 0, 0, 0);
    }
  }
  gemm_bt<3><<<dim3(DDIM / 128, (NBATCH * SEQ) / 128), 256, 0, stream>>>(
      z, ow_bf, NBATCH * SEQ, DDIM, EDIM, nullptr, out, nullptr, 0,
      x, res_scale, 0, 0, 0, 0);
}